// Round 6
// baseline (273.930 us; speedup 1.0000x reference)
//
#include <hip/hip_runtime.h>
#include <math.h>

#define B 16
#define C 512
#define L 8192
#define PP 128
#define TL 32
#define TPB 8                    // tiles per block
#define NB (L / (TL * TPB))      // 32 partial-blocks per batch
#define LN_EPS 1e-5f

typedef float fx4 __attribute__((ext_vector_type(4)));

// ---- Fused: scores + running flash softmax + partial context, all in registers. ----
// Grid (NB, B), 1024 threads. Each block sweeps 8 tiles of C x 32.
// Thread: q = tid&7 (float4 slot -> l = 4q..4q+3), r = tid>>3 (row), rows c = r+128i.
// Identical to the round-3 winner EXCEPT the phase-2 cross-lane reduce is deferred
// out of the tile loop (private accumulation; one 12-shuffle reduce at the end).
__global__ __launch_bounds__(1024, 8) void k_fused(
    const float* __restrict__ x, const float* __restrict__ cw,
    float* __restrict__ part_pc, float* __restrict__ part_m, float* __restrict__ part_z) {
  const int b = blockIdx.y;
  const int blk = blockIdx.x;
  const int tid = threadIdx.x;
  const int q = tid & 7;
  const int r = tid >> 3;
  const int lane = tid & 63;
  const int w = tid >> 6;

  __shared__ float scw[C];
  __shared__ float sred[16][32];
  __shared__ float pw[TL];
  __shared__ float s_resc;
  __shared__ float s_m, s_z;

  for (int c = tid; c < C; c += 1024) scw[c] = cw[c];
  if (tid == 0) { s_m = -INFINITY; s_z = 0.f; }

  float pc_acc[4] = {0.f, 0.f, 0.f, 0.f};
  const size_t xbase = (size_t)b * C * L;

  for (int t = 0; t < TPB; ++t) {
    const int l0 = (blk * TPB + t) * TL;
    const float4* xb4 = (const float4*)(x + xbase + l0);

    __syncthreads();   // sred/pw reuse safe; scw/s_m visible at t=0

    // Phase 1: load 4 rows x 4 l as float4, partial scores.
    float4 xv[4];
    float sp[4] = {0.f, 0.f, 0.f, 0.f};
    #pragma unroll
    for (int i = 0; i < 4; ++i) {
      const int c = r + 128 * i;
      const float4 v = xb4[(size_t)c * (L / 4) + q];
      xv[i] = v;
      const float wc = scw[c];
      sp[0] += v.x * wc; sp[1] += v.y * wc; sp[2] += v.z * wc; sp[3] += v.w * wc;
    }
    // reduce over the 8 rows within each wave (lane bits 3..5)
    #pragma unroll
    for (int m = 8; m <= 32; m <<= 1) {
      sp[0] += __shfl_xor(sp[0], m);
      sp[1] += __shfl_xor(sp[1], m);
      sp[2] += __shfl_xor(sp[2], m);
      sp[3] += __shfl_xor(sp[3], m);
    }
    if (lane < 8) {
      sred[w][4 * lane + 0] = sp[0];
      sred[w][4 * lane + 1] = sp[1];
      sred[w][4 * lane + 2] = sp[2];
      sred[w][4 * lane + 3] = sp[3];
    }
    __syncthreads();

    // Wave 0: finalize 32 scores, update running (m, z), emit pw + rescale.
    if (tid < 32) {
      float s = 0.f;
      #pragma unroll
      for (int ww = 0; ww < 16; ++ww) s += sred[ww][tid];
      float m = s;
      #pragma unroll
      for (int off = 16; off; off >>= 1) m = fmaxf(m, __shfl_xor(m, off, 32));
      const float mold = s_m;                  // read before any write
      const float mnew = fmaxf(mold, m);
      const float p = __expf(s - mnew);
      float z = p;
      #pragma unroll
      for (int off = 16; off; off >>= 1) z += __shfl_xor(z, off, 32);
      pw[tid] = p;
      if (tid == 0) {
        const float resc = __expf(mold - mnew);
        s_resc = resc;
        s_z = s_z * resc + z;
        s_m = mnew;
      }
    }
    __syncthreads();

    // Phase 2: PRIVATE weighted accumulation — no cross-lane ops in the loop.
    const float resc = s_resc;
    const float w0 = pw[4 * q + 0], w1 = pw[4 * q + 1];
    const float w2 = pw[4 * q + 2], w3 = pw[4 * q + 3];
    #pragma unroll
    for (int i = 0; i < 4; ++i) {
      const float pv = xv[i].x * w0 + xv[i].y * w1 + xv[i].z * w2 + xv[i].w * w3;
      pc_acc[i] = pc_acc[i] * resc + pv;
    }
  }

  // One-time reduce over q (lane bits 0..2).
  #pragma unroll
  for (int m = 1; m <= 4; m <<= 1) {
    #pragma unroll
    for (int i = 0; i < 4; ++i) pc_acc[i] += __shfl_xor(pc_acc[i], m);
  }
  if (q == 0) {
    float* dst = part_pc + ((size_t)(b * NB + blk)) * C;
    #pragma unroll
    for (int i = 0; i < 4; ++i) dst[r + 128 * i] = pc_acc[i];
  }
  if (tid == 0) {
    part_m[b * NB + blk] = s_m;
    part_z[b * NB + blk] = s_z;
  }
}

// ---- Tail: flash-combine 32 partials -> context -> MLP(LN,ReLU) -> add_term ----
__global__ void k_tail(const float* __restrict__ part_pc, const float* __restrict__ part_m,
                       const float* __restrict__ part_z,
                       const float* __restrict__ w1, const float* __restrict__ b1,
                       const float* __restrict__ lnw, const float* __restrict__ lnb,
                       const float* __restrict__ w2, const float* __restrict__ b2,
                       float* __restrict__ add_term) {
  const int b = blockIdx.x;
  const int tid = threadIdx.x;   // 512 threads
  __shared__ float se[NB];
  __shared__ float sctx[C];
  __shared__ float st[PP];

  if (tid < 64) {
    const float m = (tid < NB) ? part_m[b * NB + tid] : -INFINITY;
    float M = m;
    #pragma unroll
    for (int off = 16; off; off >>= 1) M = fmaxf(M, __shfl_xor(M, off, 32));
    const float e = (tid < NB) ? __expf(m - M) : 0.f;
    float Z = (tid < NB) ? part_z[b * NB + tid] * e : 0.f;
    #pragma unroll
    for (int off = 16; off; off >>= 1) Z += __shfl_xor(Z, off, 32);
    if (tid < NB) se[tid] = e / Z;
  }
  __syncthreads();

  // context[b, tid]
  float acc = 0.f;
  const float* pp = part_pc + (size_t)b * NB * C + tid;
  #pragma unroll
  for (int t = 0; t < NB; ++t) acc += pp[(size_t)t * C] * se[t];
  sctx[tid] = acc;
  __syncthreads();

  // t = w1 @ ctx + b1 (4 threads per output p)
  {
    const int p = tid >> 2;
    const int qq = tid & 3;
    const float* w1r = w1 + (size_t)p * C + qq * 128;
    const float* cx = &sctx[qq * 128];
    float a = 0.f;
    #pragma unroll 8
    for (int cc = 0; cc < 128; ++cc) a += w1r[cc] * cx[cc];
    a += __shfl_xor(a, 1);
    a += __shfl_xor(a, 2);
    if (qq == 0) st[p] = a + b1[p];
  }
  __syncthreads();

  // LayerNorm over P + ReLU
  float tv = 0.f;
  if (tid < PP) {
    float mu = 0.f;
    #pragma unroll 8
    for (int pi = 0; pi < PP; ++pi) mu += st[pi];
    mu *= (1.f / PP);
    float var = 0.f;
    #pragma unroll 8
    for (int pi = 0; pi < PP; ++pi) { const float d = st[pi] - mu; var += d * d; }
    var *= (1.f / PP);
    tv = (st[tid] - mu) * rsqrtf(var + LN_EPS) * lnw[tid] + lnb[tid];
    tv = fmaxf(tv, 0.f);
  }
  __syncthreads();
  if (tid < PP) st[tid] = tv;
  __syncthreads();

  // add_term[c] = w2[c,:] @ t + b2[c]
  float a2 = b2[tid];
  const float* w2r = w2 + (size_t)tid * PP;
  #pragma unroll 8
  for (int pi = 0; pi < PP; ++pi) a2 += w2r[pi] * st[pi];
  add_term[b * C + tid] = a2;
}

// ---- out[b,c,:] = x[b,c,:] + add_term[b,c]; NT stores keep x resident in L3 ----
__global__ void k_add(const float* __restrict__ x, const float* __restrict__ at,
                      float* __restrict__ out) {
  const int bc = blockIdx.x;
  const float a = at[bc];
  const fx4* xr = (const fx4*)(x + (size_t)bc * L);
  fx4* orow = (fx4*)(out + (size_t)bc * L);
  #pragma unroll 4
  for (int i = threadIdx.x; i < L / 4; i += 256) {
    fx4 v = xr[i];
    v = v + a;
    __builtin_nontemporal_store(v, &orow[i]);
  }
}

extern "C" void kernel_launch(void* const* d_in, const int* in_sizes, int n_in,
                              void* d_out, int out_size, void* d_ws, size_t ws_size,
                              hipStream_t stream) {
  const float* x   = (const float*)d_in[0];
  const float* cw  = (const float*)d_in[1];
  // d_in[2] (conv_mask_b) cancels exactly under softmax shift-invariance.
  const float* w1  = (const float*)d_in[3];
  const float* b1  = (const float*)d_in[4];
  const float* lnw = (const float*)d_in[5];
  const float* lnb = (const float*)d_in[6];
  const float* w2  = (const float*)d_in[7];
  const float* b2  = (const float*)d_in[8];
  float* out = (float*)d_out;

  char* ws = (char*)d_ws;
  float* part_pc  = (float*)ws;                                // B*NB*C = 1 MB
  float* part_m   = (float*)(ws + (size_t)B * NB * C * 4);
  float* part_z   = part_m + B * NB;
  float* add_term = part_z + B * NB;

  k_fused<<<dim3(NB, B), 1024, 0, stream>>>(x, cw, part_pc, part_m, part_z);
  k_tail<<<dim3(B), C, 0, stream>>>(part_pc, part_m, part_z,
                                    w1, b1, lnw, lnb, w2, b2, add_term);
  k_add<<<dim3(B * C), 256, 0, stream>>>(x, add_term, out);
}

// Round 8
// 203.378 us; speedup vs baseline: 1.3469x; 1.3469x over previous
//
#include <hip/hip_runtime.h>
#include <math.h>

#define B 16
#define C 512
#define L 8192
#define PP 128
#define TL 32
#define TPB 8                    // tiles per block
#define NB (L / (TL * TPB))      // 32 partial-blocks per batch
#define LN_EPS 1e-5f

typedef float fx4 __attribute__((ext_vector_type(4)));

// ---- Fused: scores + running flash softmax + partial context, all in registers. ----
// Grid (NB, B), 1024 threads. Each block sweeps 8 tiles of C x 32.
// Thread: q = tid&7 (float4 slot -> l = 4q..4q+3), r = tid>>3 (row), rows c = r+128i.
// NOTE: launch_bounds min-waves relaxed 8 -> 4. At (1024,8) the allocator capped the
// kernel at 32 VGPRs and spilled the xv[4] tile to scratch every iteration
// (rocprof: WRITE_SIZE 269 MB == 1024thr x 512blk x 8tiles x 64B). Cap 128 fixes it.
__global__ __launch_bounds__(1024, 4) void k_fused(
    const float* __restrict__ x, const float* __restrict__ cw,
    float* __restrict__ part_pc, float* __restrict__ part_m, float* __restrict__ part_z) {
  const int b = blockIdx.y;
  const int blk = blockIdx.x;
  const int tid = threadIdx.x;
  const int q = tid & 7;
  const int r = tid >> 3;
  const int lane = tid & 63;
  const int w = tid >> 6;

  __shared__ float scw[C];
  __shared__ float sred[16][32];
  __shared__ float pw[TL];
  __shared__ float s_resc;
  __shared__ float s_m, s_z;

  for (int c = tid; c < C; c += 1024) scw[c] = cw[c];
  if (tid == 0) { s_m = -INFINITY; s_z = 0.f; }

  float pc_acc[4] = {0.f, 0.f, 0.f, 0.f};
  const size_t xbase = (size_t)b * C * L;

  for (int t = 0; t < TPB; ++t) {
    const int l0 = (blk * TPB + t) * TL;
    const float4* xb4 = (const float4*)(x + xbase + l0);

    __syncthreads();   // sred/pw reuse safe; scw/s_m visible at t=0

    // Phase 1: load 4 rows x 4 l as float4, partial scores.
    float4 xv[4];
    float sp[4] = {0.f, 0.f, 0.f, 0.f};
    #pragma unroll
    for (int i = 0; i < 4; ++i) {
      const int c = r + 128 * i;
      const float4 v = xb4[(size_t)c * (L / 4) + q];
      xv[i] = v;
      const float wc = scw[c];
      sp[0] += v.x * wc; sp[1] += v.y * wc; sp[2] += v.z * wc; sp[3] += v.w * wc;
    }
    // reduce over the 8 rows within each wave (lane bits 3..5)
    #pragma unroll
    for (int m = 8; m <= 32; m <<= 1) {
      sp[0] += __shfl_xor(sp[0], m);
      sp[1] += __shfl_xor(sp[1], m);
      sp[2] += __shfl_xor(sp[2], m);
      sp[3] += __shfl_xor(sp[3], m);
    }
    if (lane < 8) {
      sred[w][4 * lane + 0] = sp[0];
      sred[w][4 * lane + 1] = sp[1];
      sred[w][4 * lane + 2] = sp[2];
      sred[w][4 * lane + 3] = sp[3];
    }
    __syncthreads();

    // Wave 0: finalize 32 scores, update running (m, z), emit pw + rescale.
    if (tid < 32) {
      float s = 0.f;
      #pragma unroll
      for (int ww = 0; ww < 16; ++ww) s += sred[ww][tid];
      float m = s;
      #pragma unroll
      for (int off = 16; off; off >>= 1) m = fmaxf(m, __shfl_xor(m, off, 32));
      const float mold = s_m;                  // read before any write
      const float mnew = fmaxf(mold, m);
      const float p = __expf(s - mnew);
      float z = p;
      #pragma unroll
      for (int off = 16; off; off >>= 1) z += __shfl_xor(z, off, 32);
      pw[tid] = p;
      if (tid == 0) {
        const float resc = __expf(mold - mnew);
        s_resc = resc;
        s_z = s_z * resc + z;
        s_m = mnew;
      }
    }
    __syncthreads();

    // Phase 2: PRIVATE weighted accumulation — no cross-lane ops in the loop.
    const float resc = s_resc;
    const float w0 = pw[4 * q + 0], w1 = pw[4 * q + 1];
    const float w2 = pw[4 * q + 2], w3 = pw[4 * q + 3];
    #pragma unroll
    for (int i = 0; i < 4; ++i) {
      const float pv = xv[i].x * w0 + xv[i].y * w1 + xv[i].z * w2 + xv[i].w * w3;
      pc_acc[i] = pc_acc[i] * resc + pv;
    }
  }

  // One-time reduce over q (lane bits 0..2).
  #pragma unroll
  for (int m = 1; m <= 4; m <<= 1) {
    #pragma unroll
    for (int i = 0; i < 4; ++i) pc_acc[i] += __shfl_xor(pc_acc[i], m);
  }
  if (q == 0) {
    float* dst = part_pc + ((size_t)(b * NB + blk)) * C;
    #pragma unroll
    for (int i = 0; i < 4; ++i) dst[r + 128 * i] = pc_acc[i];
  }
  if (tid == 0) {
    part_m[b * NB + blk] = s_m;
    part_z[b * NB + blk] = s_z;
  }
}

// ---- Tail: flash-combine 32 partials -> context -> MLP(LN,ReLU) -> add_term ----
__global__ void k_tail(const float* __restrict__ part_pc, const float* __restrict__ part_m,
                       const float* __restrict__ part_z,
                       const float* __restrict__ w1, const float* __restrict__ b1,
                       const float* __restrict__ lnw, const float* __restrict__ lnb,
                       const float* __restrict__ w2, const float* __restrict__ b2,
                       float* __restrict__ add_term) {
  const int b = blockIdx.x;
  const int tid = threadIdx.x;   // 512 threads
  __shared__ float se[NB];
  __shared__ float sctx[C];
  __shared__ float st[PP];

  if (tid < 64) {
    const float m = (tid < NB) ? part_m[b * NB + tid] : -INFINITY;
    float M = m;
    #pragma unroll
    for (int off = 16; off; off >>= 1) M = fmaxf(M, __shfl_xor(M, off, 32));
    const float e = (tid < NB) ? __expf(m - M) : 0.f;
    float Z = (tid < NB) ? part_z[b * NB + tid] * e : 0.f;
    #pragma unroll
    for (int off = 16; off; off >>= 1) Z += __shfl_xor(Z, off, 32);
    if (tid < NB) se[tid] = e / Z;
  }
  __syncthreads();

  // context[b, tid]
  float acc = 0.f;
  const float* pp = part_pc + (size_t)b * NB * C + tid;
  #pragma unroll
  for (int t = 0; t < NB; ++t) acc += pp[(size_t)t * C] * se[t];
  sctx[tid] = acc;
  __syncthreads();

  // t = w1 @ ctx + b1 (4 threads per output p)
  {
    const int p = tid >> 2;
    const int qq = tid & 3;
    const float* w1r = w1 + (size_t)p * C + qq * 128;
    const float* cx = &sctx[qq * 128];
    float a = 0.f;
    #pragma unroll 8
    for (int cc = 0; cc < 128; ++cc) a += w1r[cc] * cx[cc];
    a += __shfl_xor(a, 1);
    a += __shfl_xor(a, 2);
    if (qq == 0) st[p] = a + b1[p];
  }
  __syncthreads();

  // LayerNorm over P + ReLU
  float tv = 0.f;
  if (tid < PP) {
    float mu = 0.f;
    #pragma unroll 8
    for (int pi = 0; pi < PP; ++pi) mu += st[pi];
    mu *= (1.f / PP);
    float var = 0.f;
    #pragma unroll 8
    for (int pi = 0; pi < PP; ++pi) { const float d = st[pi] - mu; var += d * d; }
    var *= (1.f / PP);
    tv = (st[tid] - mu) * rsqrtf(var + LN_EPS) * lnw[tid] + lnb[tid];
    tv = fmaxf(tv, 0.f);
  }
  __syncthreads();
  if (tid < PP) st[tid] = tv;
  __syncthreads();

  // add_term[c] = w2[c,:] @ t + b2[c]
  float a2 = b2[tid];
  const float* w2r = w2 + (size_t)tid * PP;
  #pragma unroll 8
  for (int pi = 0; pi < PP; ++pi) a2 += w2r[pi] * st[pi];
  add_term[b * C + tid] = a2;
}

// ---- out[b,c,:] = x[b,c,:] + add_term[b,c]; NT stores keep x resident in L3 ----
__global__ void k_add(const float* __restrict__ x, const float* __restrict__ at,
                      float* __restrict__ out) {
  const int bc = blockIdx.x;
  const float a = at[bc];
  const fx4* xr = (const fx4*)(x + (size_t)bc * L);
  fx4* orow = (fx4*)(out + (size_t)bc * L);
  #pragma unroll 4
  for (int i = threadIdx.x; i < L / 4; i += 256) {
    fx4 v = xr[i];
    v = v + a;
    __builtin_nontemporal_store(v, &orow[i]);
  }
}

extern "C" void kernel_launch(void* const* d_in, const int* in_sizes, int n_in,
                              void* d_out, int out_size, void* d_ws, size_t ws_size,
                              hipStream_t stream) {
  const float* x   = (const float*)d_in[0];
  const float* cw  = (const float*)d_in[1];
  // d_in[2] (conv_mask_b) cancels exactly under softmax shift-invariance.
  const float* w1  = (const float*)d_in[3];
  const float* b1  = (const float*)d_in[4];
  const float* lnw = (const float*)d_in[5];
  const float* lnb = (const float*)d_in[6];
  const float* w2  = (const float*)d_in[7];
  const float* b2  = (const float*)d_in[8];
  float* out = (float*)d_out;

  char* ws = (char*)d_ws;
  float* part_pc  = (float*)ws;                                // B*NB*C = 1 MB
  float* part_m   = (float*)(ws + (size_t)B * NB * C * 4);
  float* part_z   = part_m + B * NB;
  float* add_term = part_z + B * NB;

  k_fused<<<dim3(NB, B), 1024, 0, stream>>>(x, cw, part_pc, part_m, part_z);
  k_tail<<<dim3(B), C, 0, stream>>>(part_pc, part_m, part_z,
                                    w1, b1, lnw, lnb, w2, b2, add_term);
  k_add<<<dim3(B * C), 256, 0, stream>>>(x, add_term, out);
}

// Round 9
// 158.504 us; speedup vs baseline: 1.7282x; 1.2831x over previous
//
#include <hip/hip_runtime.h>
#include <hip/hip_bf16.h>
#include <math.h>
#include <string.h>

#define B 16
#define C 512
#define L 8192
#define PP 128
#define TL 32
#define TPB 2                     // tiles per block
#define NBLK (L / (TL * TPB))     // 128 partial-blocks per batch
#define LN_EPS 1e-5f

typedef float fx4 __attribute__((ext_vector_type(4)));

static __device__ inline unsigned int pack_bf2(float a, float b) {
  __hip_bfloat16 ha = __float2bfloat16(a), hb = __float2bfloat16(b);
  unsigned short ua, ub;
  memcpy(&ua, &ha, 2); memcpy(&ub, &hb, 2);
  return ((unsigned int)ub << 16) | ua;
}
static __device__ inline float bf_lo(unsigned int u) {
  unsigned int v = u << 16; float f; memcpy(&f, &v, 4); return f;
}
static __device__ inline float bf_hi(unsigned int u) {
  unsigned int v = u & 0xffff0000u; float f; memcpy(&f, &v, 4); return f;
}

// ---- Fused: scores + per-block flash softmax + partial context. ----
// Grid (NBLK, B), 256 threads, 4 blocks/CU (LDS 35.5 KB). Nothing lives across
// barriers in registers -> structurally spill-proof (rounds 6/8 lesson).
// Phase 1: thread (q=tid&7 -> l=4q..4q+3, r=tid>>3 -> c=r+32i, i<16): float4 loads,
// fma score partials, pack bf16 pair -> LDS row [c][34 ushorts] (17 uints).
// Phase 2: thread owns c=tid, tid+256; reads its 32-l row from LDS (2-way banks, free).
__global__ __launch_bounds__(256, 4) void k_fused(
    const float* __restrict__ x, const float* __restrict__ cw,
    float* __restrict__ part_pc, float* __restrict__ part_m, float* __restrict__ part_z) {
  const int b = blockIdx.y;
  const int blk = blockIdx.x;
  const int tid = threadIdx.x;
  const int q = tid & 7;
  const int r = tid >> 3;          // 0..31
  const int lane = tid & 63;
  const int w = tid >> 6;          // wave 0..3

  __shared__ unsigned int xt[C][17];    // 34 ushorts/row (68 B stride, bank-spread)
  __shared__ float scw[C];
  __shared__ float sred[4][TL];
  __shared__ float pw[TL];
  __shared__ float s_m, s_z, s_resc;

  scw[tid] = cw[tid];
  scw[tid + 256] = cw[tid + 256];
  if (tid == 0) { s_m = -INFINITY; s_z = 0.f; }

  float pc0 = 0.f, pc1 = 0.f;
  const size_t xbase = (size_t)b * C * L;

  for (int t = 0; t < TPB; ++t) {
    const int l0 = (blk * TPB + t) * TL;
    const float4* xb4 = (const float4*)(x + xbase + l0);
    __syncthreads();                      // xt/sred/pw reuse; scw/s_m visible at t=0

    // Phase 1: stream 16 float4, score partials + bf16 stash (consume immediately).
    float sp0 = 0.f, sp1 = 0.f, sp2 = 0.f, sp3 = 0.f;
    #pragma unroll
    for (int i = 0; i < 16; ++i) {
      const int c = r + 32 * i;
      const float4 v = xb4[(size_t)c * (L / 4) + q];
      const float wc = scw[c];
      sp0 += v.x * wc; sp1 += v.y * wc; sp2 += v.z * wc; sp3 += v.w * wc;
      xt[c][2 * q]     = pack_bf2(v.x, v.y);
      xt[c][2 * q + 1] = pack_bf2(v.z, v.w);
    }
    // reduce over r within wave (lane bits 3..5)
    #pragma unroll
    for (int m = 8; m <= 32; m <<= 1) {
      sp0 += __shfl_xor(sp0, m); sp1 += __shfl_xor(sp1, m);
      sp2 += __shfl_xor(sp2, m); sp3 += __shfl_xor(sp3, m);
    }
    if (lane < 8) {
      sred[w][4 * lane + 0] = sp0;
      sred[w][4 * lane + 1] = sp1;
      sred[w][4 * lane + 2] = sp2;
      sred[w][4 * lane + 3] = sp3;
    }
    __syncthreads();

    // Wave 0 (lanes 0..31): finalize 32 scores, online softmax update.
    if (tid < 32) {
      float s = sred[0][tid] + sred[1][tid] + sred[2][tid] + sred[3][tid];
      float m = s;
      #pragma unroll
      for (int off = 16; off; off >>= 1) m = fmaxf(m, __shfl_xor(m, off, 32));
      const float mold = s_m;
      const float mnew = fmaxf(mold, m);
      const float p = __expf(s - mnew);
      float z = p;
      #pragma unroll
      for (int off = 16; off; off >>= 1) z += __shfl_xor(z, off, 32);
      pw[tid] = p;
      if (tid == 0) {
        const float e = __expf(mold - mnew);   // t=0: exp(-inf)=0 zeroes acc
        s_resc = e;
        s_z = s_z * e + z;
        s_m = mnew;
      }
    }
    __syncthreads();

    // Phase 2: thread-per-channel row sweep from LDS; 2 private accumulators.
    const float resc = s_resc;
    float a0 = 0.f, a1 = 0.f;
    #pragma unroll
    for (int j = 0; j < 16; ++j) {
      const float wl = pw[2 * j], wh = pw[2 * j + 1];
      const unsigned int u0 = xt[tid][j];
      const unsigned int u1 = xt[tid + 256][j];
      a0 += bf_lo(u0) * wl + bf_hi(u0) * wh;
      a1 += bf_lo(u1) * wl + bf_hi(u1) * wh;
    }
    pc0 = pc0 * resc + a0;
    pc1 = pc1 * resc + a1;
  }

  float* dst = part_pc + (size_t)(b * NBLK + blk) * C;
  dst[tid] = pc0;
  dst[tid + 256] = pc1;
  if (tid == 0) {
    part_m[b * NBLK + blk] = s_m;
    part_z[b * NBLK + blk] = s_z;
  }
}

// ---- Tail: flash-combine 128 partials -> context -> MLP(LN,ReLU) -> add_term ----
__global__ void k_tail(const float* __restrict__ part_pc, const float* __restrict__ part_m,
                       const float* __restrict__ part_z,
                       const float* __restrict__ w1, const float* __restrict__ b1,
                       const float* __restrict__ lnw, const float* __restrict__ lnb,
                       const float* __restrict__ w2, const float* __restrict__ b2,
                       float* __restrict__ add_term) {
  const int b = blockIdx.x;
  const int tid = threadIdx.x;   // 512 threads
  __shared__ float se[NBLK];
  __shared__ float sMZ[2];
  __shared__ float sctx[C];
  __shared__ float st[PP];

  const float* pm = part_m + b * NBLK;
  const float* pz = part_z + b * NBLK;

  if (tid < 64) {
    const float m0 = pm[tid], m1 = pm[tid + 64];
    float mm = fmaxf(m0, m1);
    #pragma unroll
    for (int off = 32; off; off >>= 1) mm = fmaxf(mm, __shfl_xor(mm, off));
    float z = pz[tid] * __expf(m0 - mm) + pz[tid + 64] * __expf(m1 - mm);
    #pragma unroll
    for (int off = 32; off; off >>= 1) z += __shfl_xor(z, off);
    if (tid == 0) { sMZ[0] = mm; sMZ[1] = z; }
  }
  __syncthreads();
  const float M = sMZ[0];
  const float Zinv = 1.f / sMZ[1];
  if (tid < NBLK) se[tid] = __expf(pm[tid] - M) * Zinv;
  __syncthreads();

  // context[b, tid]
  float acc = 0.f;
  const float* pp = part_pc + (size_t)b * NBLK * C + tid;
  #pragma unroll 4
  for (int t = 0; t < NBLK; ++t) acc += pp[(size_t)t * C] * se[t];
  sctx[tid] = acc;
  __syncthreads();

  // t = w1 @ ctx + b1 (4 threads per output p)
  {
    const int p = tid >> 2;
    const int qq = tid & 3;
    const float* w1r = w1 + (size_t)p * C + qq * 128;
    const float* cx = &sctx[qq * 128];
    float a = 0.f;
    #pragma unroll 8
    for (int cc = 0; cc < 128; ++cc) a += w1r[cc] * cx[cc];
    a += __shfl_xor(a, 1);
    a += __shfl_xor(a, 2);
    if (qq == 0) st[p] = a + b1[p];
  }
  __syncthreads();

  // LayerNorm over P + ReLU
  float tv = 0.f;
  if (tid < PP) {
    float mu = 0.f;
    #pragma unroll 8
    for (int pi = 0; pi < PP; ++pi) mu += st[pi];
    mu *= (1.f / PP);
    float var = 0.f;
    #pragma unroll 8
    for (int pi = 0; pi < PP; ++pi) { const float d = st[pi] - mu; var += d * d; }
    var *= (1.f / PP);
    tv = (st[tid] - mu) * rsqrtf(var + LN_EPS) * lnw[tid] + lnb[tid];
    tv = fmaxf(tv, 0.f);
  }
  __syncthreads();
  if (tid < PP) st[tid] = tv;
  __syncthreads();

  // add_term[c] = w2[c,:] @ t + b2[c]
  float a2 = b2[tid];
  const float* w2r = w2 + (size_t)tid * PP;
  #pragma unroll 8
  for (int pi = 0; pi < PP; ++pi) a2 += w2r[pi] * st[pi];
  add_term[b * C + tid] = a2;
}

// ---- out[b,c,:] = x[b,c,:] + add_term[b,c]; NT stores keep x resident in L3 ----
__global__ void k_add(const float* __restrict__ x, const float* __restrict__ at,
                      float* __restrict__ out) {
  const int bc = blockIdx.x;
  const float a = at[bc];
  const fx4* xr = (const fx4*)(x + (size_t)bc * L);
  fx4* orow = (fx4*)(out + (size_t)bc * L);
  #pragma unroll 4
  for (int i = threadIdx.x; i < L / 4; i += 256) {
    fx4 v = xr[i];
    v = v + a;
    __builtin_nontemporal_store(v, &orow[i]);
  }
}

extern "C" void kernel_launch(void* const* d_in, const int* in_sizes, int n_in,
                              void* d_out, int out_size, void* d_ws, size_t ws_size,
                              hipStream_t stream) {
  const float* x   = (const float*)d_in[0];
  const float* cw  = (const float*)d_in[1];
  // d_in[2] (conv_mask_b) cancels exactly under softmax shift-invariance.
  const float* w1  = (const float*)d_in[3];
  const float* b1  = (const float*)d_in[4];
  const float* lnw = (const float*)d_in[5];
  const float* lnb = (const float*)d_in[6];
  const float* w2  = (const float*)d_in[7];
  const float* b2  = (const float*)d_in[8];
  float* out = (float*)d_out;

  char* ws = (char*)d_ws;
  float* part_pc  = (float*)ws;                                  // B*NBLK*C = 4 MB
  float* part_m   = (float*)(ws + (size_t)B * NBLK * C * 4);     // 8 KB
  float* part_z   = part_m + B * NBLK;
  float* add_term = part_z + B * NBLK;                           // 32 KB

  k_fused<<<dim3(NBLK, B), 256, 0, stream>>>(x, cw, part_pc, part_m, part_z);
  k_tail<<<dim3(B), C, 0, stream>>>(part_pc, part_m, part_z,
                                    w1, b1, lnw, lnb, w2, b2, add_term);
  k_add<<<dim3(B * C), 256, 0, stream>>>(x, add_term, out);
}

// Round 10
// 157.529 us; speedup vs baseline: 1.7389x; 1.0062x over previous
//
#include <hip/hip_runtime.h>
#include <hip/hip_bf16.h>
#include <math.h>
#include <string.h>

#define B 16
#define C 512
#define L 8192
#define PP 128
#define TL 32
#define TPB 2                     // tiles per block
#define NBLK (L / (TL * TPB))     // 128 partial-blocks per batch
#define LN_EPS 1e-5f

typedef float fx4 __attribute__((ext_vector_type(4)));

static __device__ inline unsigned int pack_bf2(float a, float b) {
  __hip_bfloat16 ha = __float2bfloat16(a), hb = __float2bfloat16(b);
  unsigned short ua, ub;
  memcpy(&ua, &ha, 2); memcpy(&ub, &hb, 2);
  return ((unsigned int)ub << 16) | ua;
}
static __device__ inline float bf_lo(unsigned int u) {
  unsigned int v = u << 16; float f; memcpy(&f, &v, 4); return f;
}
static __device__ inline float bf_hi(unsigned int u) {
  unsigned int v = u & 0xffff0000u; float f; memcpy(&f, &v, 4); return f;
}

// ---- Fused: scores + per-block flash softmax + partial context. ----
// Grid (NBLK, B), 256 threads, 4 blocks/CU (LDS 35.5 KB). Nothing lives across
// barriers in registers -> structurally spill-proof (rounds 6/8 lesson).
__global__ __launch_bounds__(256, 4) void k_fused(
    const float* __restrict__ x, const float* __restrict__ cw,
    float* __restrict__ part_pc, float* __restrict__ part_m, float* __restrict__ part_z) {
  const int b = blockIdx.y;
  const int blk = blockIdx.x;
  const int tid = threadIdx.x;
  const int q = tid & 7;
  const int r = tid >> 3;          // 0..31
  const int lane = tid & 63;
  const int w = tid >> 6;          // wave 0..3

  __shared__ unsigned int xt[C][17];    // 34 ushorts/row (68 B stride, bank-spread)
  __shared__ float scw[C];
  __shared__ float sred[4][TL];
  __shared__ float pw[TL];
  __shared__ float s_m, s_z, s_resc;

  scw[tid] = cw[tid];
  scw[tid + 256] = cw[tid + 256];
  if (tid == 0) { s_m = -INFINITY; s_z = 0.f; }

  float pc0 = 0.f, pc1 = 0.f;
  const size_t xbase = (size_t)b * C * L;

  for (int t = 0; t < TPB; ++t) {
    const int l0 = (blk * TPB + t) * TL;
    const float4* xb4 = (const float4*)(x + xbase + l0);
    __syncthreads();                      // xt/sred/pw reuse; scw/s_m visible at t=0

    // Phase 1: stream 16 float4, score partials + bf16 stash (consume immediately).
    float sp0 = 0.f, sp1 = 0.f, sp2 = 0.f, sp3 = 0.f;
    #pragma unroll
    for (int i = 0; i < 16; ++i) {
      const int c = r + 32 * i;
      const float4 v = xb4[(size_t)c * (L / 4) + q];
      const float wc = scw[c];
      sp0 += v.x * wc; sp1 += v.y * wc; sp2 += v.z * wc; sp3 += v.w * wc;
      xt[c][2 * q]     = pack_bf2(v.x, v.y);
      xt[c][2 * q + 1] = pack_bf2(v.z, v.w);
    }
    // reduce over r within wave (lane bits 3..5)
    #pragma unroll
    for (int m = 8; m <= 32; m <<= 1) {
      sp0 += __shfl_xor(sp0, m); sp1 += __shfl_xor(sp1, m);
      sp2 += __shfl_xor(sp2, m); sp3 += __shfl_xor(sp3, m);
    }
    if (lane < 8) {
      sred[w][4 * lane + 0] = sp0;
      sred[w][4 * lane + 1] = sp1;
      sred[w][4 * lane + 2] = sp2;
      sred[w][4 * lane + 3] = sp3;
    }
    __syncthreads();

    // Wave 0 (lanes 0..31): finalize 32 scores, online softmax update.
    if (tid < 32) {
      float s = sred[0][tid] + sred[1][tid] + sred[2][tid] + sred[3][tid];
      float m = s;
      #pragma unroll
      for (int off = 16; off; off >>= 1) m = fmaxf(m, __shfl_xor(m, off, 32));
      const float mold = s_m;
      const float mnew = fmaxf(mold, m);
      const float p = __expf(s - mnew);
      float z = p;
      #pragma unroll
      for (int off = 16; off; off >>= 1) z += __shfl_xor(z, off, 32);
      pw[tid] = p;
      if (tid == 0) {
        const float e = __expf(mold - mnew);   // t=0: exp(-inf)=0 zeroes acc
        s_resc = e;
        s_z = s_z * e + z;
        s_m = mnew;
      }
    }
    __syncthreads();

    // Phase 2: thread-per-channel row sweep from LDS; 2 private accumulators.
    const float resc = s_resc;
    float a0 = 0.f, a1 = 0.f;
    #pragma unroll
    for (int j = 0; j < 16; ++j) {
      const float wl = pw[2 * j], wh = pw[2 * j + 1];
      const unsigned int u0 = xt[tid][j];
      const unsigned int u1 = xt[tid + 256][j];
      a0 += bf_lo(u0) * wl + bf_hi(u0) * wh;
      a1 += bf_lo(u1) * wl + bf_hi(u1) * wh;
    }
    pc0 = pc0 * resc + a0;
    pc1 = pc1 * resc + a1;
  }

  float* dst = part_pc + (size_t)(b * NBLK + blk) * C;
  dst[tid] = pc0;
  dst[tid + 256] = pc1;
  if (tid == 0) {
    part_m[b * NBLK + blk] = s_m;
    part_z[b * NBLK + blk] = s_z;
  }
}

// ---- Tail: flash-combine 128 partials -> context -> MLP(LN,ReLU) -> add_term ----
__global__ void k_tail(const float* __restrict__ part_pc, const float* __restrict__ part_m,
                       const float* __restrict__ part_z,
                       const float* __restrict__ w1, const float* __restrict__ b1,
                       const float* __restrict__ lnw, const float* __restrict__ lnb,
                       const float* __restrict__ w2, const float* __restrict__ b2,
                       float* __restrict__ add_term) {
  const int b = blockIdx.x;
  const int tid = threadIdx.x;   // 512 threads
  __shared__ float se[NBLK];
  __shared__ float sMZ[2];
  __shared__ float sctx[C];
  __shared__ float st[PP];

  const float* pm = part_m + b * NBLK;
  const float* pz = part_z + b * NBLK;

  if (tid < 64) {
    const float m0 = pm[tid], m1 = pm[tid + 64];
    float mm = fmaxf(m0, m1);
    #pragma unroll
    for (int off = 32; off; off >>= 1) mm = fmaxf(mm, __shfl_xor(mm, off));
    float z = pz[tid] * __expf(m0 - mm) + pz[tid + 64] * __expf(m1 - mm);
    #pragma unroll
    for (int off = 32; off; off >>= 1) z += __shfl_xor(z, off);
    if (tid == 0) { sMZ[0] = mm; sMZ[1] = z; }
  }
  __syncthreads();
  const float M = sMZ[0];
  const float Zinv = 1.f / sMZ[1];
  if (tid < NBLK) se[tid] = __expf(pm[tid] - M) * Zinv;
  __syncthreads();

  // context[b, tid]
  float acc = 0.f;
  const float* pp = part_pc + (size_t)b * NBLK * C + tid;
  #pragma unroll 4
  for (int t = 0; t < NBLK; ++t) acc += pp[(size_t)t * C] * se[t];
  sctx[tid] = acc;
  __syncthreads();

  // t = w1 @ ctx + b1 (4 threads per output p)
  {
    const int p = tid >> 2;
    const int qq = tid & 3;
    const float* w1r = w1 + (size_t)p * C + qq * 128;
    const float* cx = &sctx[qq * 128];
    float a = 0.f;
    #pragma unroll 8
    for (int cc = 0; cc < 128; ++cc) a += w1r[cc] * cx[cc];
    a += __shfl_xor(a, 1);
    a += __shfl_xor(a, 2);
    if (qq == 0) st[p] = a + b1[p];
  }
  __syncthreads();

  // LayerNorm over P + ReLU
  float tv = 0.f;
  if (tid < PP) {
    float mu = 0.f;
    #pragma unroll 8
    for (int pi = 0; pi < PP; ++pi) mu += st[pi];
    mu *= (1.f / PP);
    float var = 0.f;
    #pragma unroll 8
    for (int pi = 0; pi < PP; ++pi) { const float d = st[pi] - mu; var += d * d; }
    var *= (1.f / PP);
    tv = (st[tid] - mu) * rsqrtf(var + LN_EPS) * lnw[tid] + lnb[tid];
    tv = fmaxf(tv, 0.f);
  }
  __syncthreads();
  if (tid < PP) st[tid] = tv;
  __syncthreads();

  // add_term[c] = w2[c,:] @ t + b2[c]
  float a2 = b2[tid];
  const float* w2r = w2 + (size_t)tid * PP;
  #pragma unroll 8
  for (int pi = 0; pi < PP; ++pi) a2 += w2r[pi] * st[pi];
  add_term[b * C + tid] = a2;
}

// ---- out[row,:] = x[row,:] + add_term[row], REVERSE row order for L3 reuse. ----
// k_fused streams x forward through L3 (256 MiB == |x|); forward re-read would be
// the LRU worst case (head evicted by tail). Reversed, the first adds hit the
// most-recently-cached tail. NT stores keep `out` from evicting x.
__global__ void k_add(const float* __restrict__ x, const float* __restrict__ at,
                      float* __restrict__ out) {
  const int bc = (B * C - 1) - blockIdx.x;     // reverse traversal
  const float a = at[bc];
  const fx4* xr = (const fx4*)(x + (size_t)bc * L);
  fx4* orow = (fx4*)(out + (size_t)bc * L);
  #pragma unroll 4
  for (int i = threadIdx.x; i < L / 4; i += 256) {
    fx4 v = xr[i];
    v = v + a;
    __builtin_nontemporal_store(v, &orow[i]);
  }
}

extern "C" void kernel_launch(void* const* d_in, const int* in_sizes, int n_in,
                              void* d_out, int out_size, void* d_ws, size_t ws_size,
                              hipStream_t stream) {
  const float* x   = (const float*)d_in[0];
  const float* cw  = (const float*)d_in[1];
  // d_in[2] (conv_mask_b) cancels exactly under softmax shift-invariance.
  const float* w1  = (const float*)d_in[3];
  const float* b1  = (const float*)d_in[4];
  const float* lnw = (const float*)d_in[5];
  const float* lnb = (const float*)d_in[6];
  const float* w2  = (const float*)d_in[7];
  const float* b2  = (const float*)d_in[8];
  float* out = (float*)d_out;

  char* ws = (char*)d_ws;
  float* part_pc  = (float*)ws;                                  // B*NBLK*C = 4 MB
  float* part_m   = (float*)(ws + (size_t)B * NBLK * C * 4);     // 8 KB
  float* part_z   = part_m + B * NBLK;
  float* add_term = part_z + B * NBLK;                           // 32 KB

  k_fused<<<dim3(NBLK, B), 256, 0, stream>>>(x, cw, part_pc, part_m, part_z);
  k_tail<<<dim3(B), C, 0, stream>>>(part_pc, part_m, part_z,
                                    w1, b1, lnw, lnb, w2, b2, add_term);
  k_add<<<dim3(B * C), 256, 0, stream>>>(x, add_term, out);
}